// Round 12
// baseline (38.621 us; speedup 1.0000x reference)
//
#include <hip/hip_runtime.h>
#include <stdint.h>

#define NQ 900
#define TOPK_PRE 100
#define TOPK_POST 20
#define IOU_THR 0.7f
#define THREADS 512

typedef unsigned long long u64;

__device__ __forceinline__ u64 umin64(u64 a, u64 b) { return a < b ? a : b; }
__device__ __forceinline__ u64 umax64(u64 a, u64 b) { return a > b ? a : b; }

__device__ __forceinline__ void ce(u64& v, int j, bool up, int lane) {
    u64 part = __shfl_xor(v, j);
    bool lower = ((lane & j) == 0);
    v = (up == lower) ? umin64(v, part) : umax64(v, part);
}

// merge two sorted-ascending 128-lists (in LDS) -> sorted ascending top-128 in (c0,c1)
__device__ __forceinline__ void merge_lds(const u64* __restrict__ A,
                                          const u64* __restrict__ B,
                                          u64& c0, u64& c1, int lane) {
    c0 = umin64(A[lane],      B[127 - lane]);
    c1 = umin64(A[64 + lane], B[63 - lane]);
    u64 lo = umin64(c0, c1), hi = umax64(c0, c1);   // j = 64 (reg-local)
    c0 = lo; c1 = hi;
#pragma unroll
    for (int j = 32; j > 0; j >>= 1) {
        bool lower = (lane & j) == 0;
        u64 p0 = __shfl_xor(c0, j);
        u64 p1 = __shfl_xor(c1, j);
        c0 = lower ? umin64(c0, p0) : umax64(c0, p0);
        c1 = lower ? umin64(c1, p1) : umax64(c1, p1);
    }
}

// Output layout (float32):
//   sel_s : [0,      20480)   (16,64,20)
//   sel_b : [20480, 102400)   (16,64,20,4)
//   sel_l : [102400,122880)   (16,64,20)
//   vmask : [122880,143360)   (16,64,20)

__global__ __launch_bounds__(THREADS)
void ovnms_kernel(const float* __restrict__ logits,   // (16,1,57600,2)
                  const float* __restrict__ boxes,    // (16,1,57600,4)
                  const float* __restrict__ tsize,    // (16,2) [h,w]
                  const int*   __restrict__ labels,   // (16,64)
                  float* __restrict__ out)
{
#pragma clang fp contract(off)
    const int row  = blockIdx.x;       // b*64 + p
    const int b    = row >> 6;
    const int p    = row & 63;
    const int tid  = threadIdx.x;
    const int lane = tid & 63;
    const int wid  = tid >> 6;         // 0..7

    __shared__ u64 wl[8 * 128];        // per-wave sorted 128-lists
    __shared__ u64 md[4 * 128];
    __shared__ u64 m2[2 * 128];
    __shared__ u64 fin[128];
    __shared__ float x1s[TOPK_PRE], y1s[TOPK_PRE], x2s[TOPK_PRE], y2s[TOPK_PRE];
    __shared__ float areas[TOPK_PRE], scs[TOPK_PRE];
    __shared__ u64 sup0[TOPK_PRE], sup1[TOPK_PRE];
    __shared__ u64 keep0s, keep1s;

    const size_t brow0 = (size_t)b * 57600 + (size_t)p * NQ;

    // ---- 0. hoist tiny uniform loads — latency hides under the sort ----
    const float ih  = tsize[b * 2 + 0];
    const float iw  = tsize[b * 2 + 1];
    const float lab_f = (float)labels[row];

    // ---- 1. sigmoid scores -> 2 keys per lane ----
    const float* lrow = logits + brow0 * 2;
    u64 c0, c1;
    {
        int q0 = wid * 128 + lane;
        int q1 = q0 + 64;
        u64 k0 = ~0ull, k1 = ~0ull;
        if (q0 < NQ) {
            float x = lrow[q0 * 2 + 1];
            float s = 1.0f / (1.0f + expf(-x));
            k0 = ((u64)(~__float_as_uint(s)) << 32) | (unsigned)q0;
        }
        if (q1 < NQ) {
            float x = lrow[q1 * 2 + 1];
            float s = 1.0f / (1.0f + expf(-x));
            k1 = ((u64)(~__float_as_uint(s)) << 32) | (unsigned)q1;
        }
        c0 = k0; c1 = k1;
    }

    // ---- 2. in-wave bitonic sort of 128 keys ascending ----
#pragma unroll
    for (int k = 2; k <= 64; k <<= 1) {
#pragma unroll
        for (int j = k >> 1; j > 0; j >>= 1) {
            ce(c0, j, (lane & k) == 0, lane);
            ce(c1, j, ((64 + lane) & k) == 0, lane);
        }
    }
    {   // k = 128
        u64 lo = umin64(c0, c1), hi = umax64(c0, c1);
        c0 = lo; c1 = hi;
#pragma unroll
        for (int j = 32; j > 0; j >>= 1) {
            ce(c0, j, true, lane);
            ce(c1, j, true, lane);
        }
    }

    wl[wid * 128 + lane]      = c0;
    wl[wid * 128 + 64 + lane] = c1;
    __syncthreads();

    // ---- 3. merge tree 8 -> 4 -> 2 -> 1 ----
    if (wid < 4) {
        u64 a0, a1;
        merge_lds(&wl[(2 * wid) * 128], &wl[(2 * wid + 1) * 128], a0, a1, lane);
        md[wid * 128 + lane]      = a0;
        md[wid * 128 + 64 + lane] = a1;
    }
    __syncthreads();
    if (wid < 2) {
        u64 a0, a1;
        merge_lds(&md[(2 * wid) * 128], &md[(2 * wid + 1) * 128], a0, a1, lane);
        m2[wid * 128 + lane]      = a0;
        m2[wid * 128 + 64 + lane] = a1;
    }
    __syncthreads();
    if (wid == 0) {
        u64 a0, a1;
        merge_lds(m2, m2 + 128, a0, a1, lane);
        fin[lane]      = a0;
        fin[64 + lane] = a1;
    }
    __syncthreads();

    // ---- 4. gather top-100 boxes (float4), scale, areas ----
    if (tid < TOPK_PRE) {
        u64 key = fin[tid];
        int q = (int)(key & 0xFFFFFFFFu);
        scs[tid] = __uint_as_float(~(unsigned)(key >> 32));
        float4 bx = ((const float4*)boxes)[brow0 + (size_t)q];
        float cx = bx.x, cy = bx.y, w = bx.z, h = bx.w;
        float xa = (cx - 0.5f * w) * iw;
        float ya = (cy - 0.5f * h) * ih;
        float xb = (cx + 0.5f * w) * iw;
        float yb = (cy + 0.5f * h) * ih;
        x1s[tid] = xa; y1s[tid] = ya; x2s[tid] = xb; y2s[tid] = yb;
        areas[tid] = fmaxf(xb - xa, 0.0f) * fmaxf(yb - ya, 0.0f);
    }
    __syncthreads();

    // ---- 5. suppression bit-matrix via ballot (8 waves, stride 8) ----
    {
        const float xj1a = x1s[lane], yj1a = y1s[lane];
        const float xj2a = x2s[lane], yj2a = y2s[lane], aja = areas[lane];
        const int  j2   = lane + 64;
        const bool hv2  = j2 < TOPK_PRE;
        const int  j2c  = hv2 ? j2 : 0;
        const float xj1b = x1s[j2c], yj1b = y1s[j2c];
        const float xj2b = x2s[j2c], yj2b = y2s[j2c], ajb = areas[j2c];

#pragma unroll 4
        for (int i = wid; i < TOPK_PRE; i += 8) {
            float xi1 = x1s[i], yi1 = y1s[i], xi2 = x2s[i], yi2 = y2s[i], ai = areas[i];
            bool b0 = false;
            if (lane < i) {
                float ltx = fmaxf(xi1, xj1a);
                float lty = fmaxf(yi1, yj1a);
                float rbx = fminf(xi2, xj2a);
                float rby = fminf(yi2, yj2a);
                float wx = fmaxf(rbx - ltx, 0.0f);
                float wy = fmaxf(rby - lty, 0.0f);
                float inter = wx * wy;
                float iou = inter / (((ai + aja) - inter) + 1e-7f);
                b0 = iou > IOU_THR;
            }
            u64 m0 = __ballot(b0);
            bool b1 = false;
            if (hv2 && j2 < i) {
                float ltx = fmaxf(xi1, xj1b);
                float lty = fmaxf(yi1, yj1b);
                float rbx = fminf(xi2, xj2b);
                float rby = fminf(yi2, yj2b);
                float wx = fmaxf(rbx - ltx, 0.0f);
                float wy = fmaxf(rby - lty, 0.0f);
                float inter = wx * wy;
                float iou = inter / (((ai + ajb) - inter) + 1e-7f);
                b1 = iou > IOU_THR;
            }
            u64 m1 = __ballot(b1);
            if (lane == 0) { sup0[i] = m0; sup1[i] = m1; }
        }
    }
    __syncthreads();

    // ---- 6. greedy scan with ffs-skip over alive candidates (wave 0) ----
    if (wid == 0) {
        u64 r0a = sup0[lane];
        u64 r1a = sup1[lane];
        const int  j2  = lane + 64;
        const bool hv2 = j2 < TOPK_PRE;
        u64 r0b = hv2 ? sup0[j2] : 0ull;
        u64 r1b = hv2 ? sup1[j2] : 0ull;
        bool alive_a = true;
        bool alive_b = hv2;

        {
            int i = 0;
            for (;;) {
                u64 act = __ballot(alive_a) & (~0ull << i);
                if (!act) break;
                i = __ffsll(act) - 1;
                alive_a = alive_a && !((r0a >> i) & 1ull);
                alive_b = alive_b && !((r0b >> i) & 1ull);
                if (++i >= 64) break;
            }
        }
        {
            int i = 0;
            for (;;) {
                u64 act = __ballot(alive_b) & (~0ull << i);
                if (!act) break;
                int m = __ffsll(act) - 1;
                if (m >= TOPK_PRE - 64) break;
                alive_a = alive_a && !((r1a >> m) & 1ull);
                alive_b = alive_b && !((r1b >> m) & 1ull);
                i = m + 1;
                if (i >= TOPK_PRE - 64) break;
            }
        }
        u64 B0 = __ballot(alive_a);
        u64 B1 = __ballot(alive_b);
        if (lane == 0) { keep0s = B0; keep1s = B1; }
    }
    __syncthreads();

    // ---- 7. write outputs: thread t takes the t-th kept row ----
    if (tid < TOPK_POST) {
        u64 K0 = keep0s, K1 = keep1s;
        int c0n = __popcll(K0);
        int idx = -1;
        if (tid < c0n) {
            u64 x = K0;
            for (int k = 0; k < tid; ++k) x &= x - 1;
            idx = __ffsll(x) - 1;
        } else {
            int t = tid - c0n;
            if (t < __popcll(K1)) {
                u64 x = K1;
                for (int k = 0; k < t; ++k) x &= x - 1;
                idx = 64 + __ffsll(x) - 1;
            }
        }
        size_t o = (size_t)row * TOPK_POST + (size_t)tid;
        float s = 0.0f, xa = 0.0f, ya = 0.0f, xb = 0.0f, yb = 0.0f;
        float lab = -1.0f, m = 0.0f;
        if (idx >= 0) {
            s = scs[idx];
            xa = x1s[idx]; ya = y1s[idx]; xb = x2s[idx]; yb = y2s[idx];
            lab = lab_f;
            m = 1.0f;
        }
        out[o] = s;
        float* ob = out + 20480 + o * 4;
        ob[0] = xa; ob[1] = ya; ob[2] = xb; ob[3] = yb;
        out[102400 + o] = lab;
        out[122880 + o] = m;
    }
}

extern "C" void kernel_launch(void* const* d_in, const int* in_sizes, int n_in,
                              void* d_out, int out_size, void* d_ws, size_t ws_size,
                              hipStream_t stream) {
    const float* logits = (const float*)d_in[0];
    const float* boxes  = (const float*)d_in[1];
    const float* tsize  = (const float*)d_in[2];
    const int*   labels = (const int*)d_in[3];
    float* out = (float*)d_out;

    ovnms_kernel<<<dim3(1024), dim3(THREADS), 0, stream>>>(logits, boxes, tsize, labels, out);
}

// Round 13
// 38.302 us; speedup vs baseline: 1.0083x; 1.0083x over previous
//
#include <hip/hip_runtime.h>
#include <stdint.h>

#define NQ 900
#define TOPK_PRE 100
#define TOPK_POST 20
#define IOU_THR 0.7f
#define THREADS 512

typedef unsigned long long u64;

__device__ __forceinline__ u64 umin64(u64 a, u64 b) { return a < b ? a : b; }
__device__ __forceinline__ u64 umax64(u64 a, u64 b) { return a > b ? a : b; }

__device__ __forceinline__ void ce(u64& v, int j, bool up, int lane) {
    u64 part = __shfl_xor(v, j);
    bool lower = ((lane & j) == 0);
    v = (up == lower) ? umin64(v, part) : umax64(v, part);
}

// merge two sorted-ascending 128-lists (in LDS) -> sorted ascending top-128 in (c0,c1)
__device__ __forceinline__ void merge_lds(const u64* __restrict__ A,
                                          const u64* __restrict__ B,
                                          u64& c0, u64& c1, int lane) {
    c0 = umin64(A[lane],      B[127 - lane]);
    c1 = umin64(A[64 + lane], B[63 - lane]);
    u64 lo = umin64(c0, c1), hi = umax64(c0, c1);   // j = 64 (reg-local)
    c0 = lo; c1 = hi;
#pragma unroll
    for (int j = 32; j > 0; j >>= 1) {
        bool lower = (lane & j) == 0;
        u64 p0 = __shfl_xor(c0, j);
        u64 p1 = __shfl_xor(c1, j);
        c0 = lower ? umin64(c0, p0) : umax64(c0, p0);
        c1 = lower ? umin64(c1, p1) : umax64(c1, p1);
    }
}

// Output layout (float32):
//   sel_s : [0,      20480)   (16,64,20)
//   sel_b : [20480, 102400)   (16,64,20,4)
//   sel_l : [102400,122880)   (16,64,20)
//   vmask : [122880,143360)   (16,64,20)

__global__ __launch_bounds__(THREADS)
void ovnms_kernel(const float* __restrict__ logits,   // (16,1,57600,2)
                  const float* __restrict__ boxes,    // (16,1,57600,4)
                  const float* __restrict__ tsize,    // (16,2) [h,w]
                  const int*   __restrict__ labels,   // (16,64)
                  float* __restrict__ out)
{
#pragma clang fp contract(off)
    const int row  = blockIdx.x;       // b*64 + p
    const int b    = row >> 6;
    const int p    = row & 63;
    const int tid  = threadIdx.x;
    const int lane = tid & 63;
    const int wid  = tid >> 6;         // 0..7

    __shared__ u64 wl[8 * 128];        // per-wave sorted 128-lists
    __shared__ u64 md[4 * 128];
    __shared__ u64 m2[2 * 128];
    __shared__ u64 fin[128];
    __shared__ float x1s[TOPK_PRE], y1s[TOPK_PRE], x2s[TOPK_PRE], y2s[TOPK_PRE];
    __shared__ float areas[TOPK_PRE], scs[TOPK_PRE];
    __shared__ u64 sup0[TOPK_PRE], sup1[TOPK_PRE];
    __shared__ u64 keep0s, keep1s;

    const size_t brow0 = (size_t)b * 57600 + (size_t)p * NQ;

    // ---- 1. sigmoid scores -> 2 keys per lane ----
    const float* lrow = logits + brow0 * 2;
    u64 c0, c1;
    {
        int q0 = wid * 128 + lane;
        int q1 = q0 + 64;
        u64 k0 = ~0ull, k1 = ~0ull;
        if (q0 < NQ) {
            float x = lrow[q0 * 2 + 1];
            float s = 1.0f / (1.0f + expf(-x));
            k0 = ((u64)(~__float_as_uint(s)) << 32) | (unsigned)q0;
        }
        if (q1 < NQ) {
            float x = lrow[q1 * 2 + 1];
            float s = 1.0f / (1.0f + expf(-x));
            k1 = ((u64)(~__float_as_uint(s)) << 32) | (unsigned)q1;
        }
        c0 = k0; c1 = k1;
    }

    // ---- 2. in-wave bitonic sort of 128 keys ascending ----
#pragma unroll
    for (int k = 2; k <= 64; k <<= 1) {
#pragma unroll
        for (int j = k >> 1; j > 0; j >>= 1) {
            ce(c0, j, (lane & k) == 0, lane);
            ce(c1, j, ((64 + lane) & k) == 0, lane);
        }
    }
    {   // k = 128
        u64 lo = umin64(c0, c1), hi = umax64(c0, c1);
        c0 = lo; c1 = hi;
#pragma unroll
        for (int j = 32; j > 0; j >>= 1) {
            ce(c0, j, true, lane);
            ce(c1, j, true, lane);
        }
    }

    wl[wid * 128 + lane]      = c0;
    wl[wid * 128 + 64 + lane] = c1;
    __syncthreads();

    // ---- 3. merge tree 8 -> 4 -> 2 -> 1 ----
    if (wid < 4) {
        u64 a0, a1;
        merge_lds(&wl[(2 * wid) * 128], &wl[(2 * wid + 1) * 128], a0, a1, lane);
        md[wid * 128 + lane]      = a0;
        md[wid * 128 + 64 + lane] = a1;
    }
    __syncthreads();
    if (wid < 2) {
        u64 a0, a1;
        merge_lds(&md[(2 * wid) * 128], &md[(2 * wid + 1) * 128], a0, a1, lane);
        m2[wid * 128 + lane]      = a0;
        m2[wid * 128 + 64 + lane] = a1;
    }
    __syncthreads();
    if (wid == 0) {
        u64 a0, a1;
        merge_lds(m2, m2 + 128, a0, a1, lane);
        fin[lane]      = a0;
        fin[64 + lane] = a1;
    }
    __syncthreads();

    // ---- 4. gather top-100 boxes, scale, areas ----
    if (tid < TOPK_PRE) {
        u64 key = fin[tid];
        int q = (int)(key & 0xFFFFFFFFu);
        scs[tid] = __uint_as_float(~(unsigned)(key >> 32));
        const float* brow = boxes + ((size_t)b * 57600 + (size_t)p * NQ + (size_t)q) * 4;
        float cx = brow[0], cy = brow[1], w = brow[2], h = brow[3];
        float ih = tsize[b * 2 + 0];
        float iw = tsize[b * 2 + 1];
        float xa = (cx - 0.5f * w) * iw;
        float ya = (cy - 0.5f * h) * ih;
        float xb = (cx + 0.5f * w) * iw;
        float yb = (cy + 0.5f * h) * ih;
        x1s[tid] = xa; y1s[tid] = ya; x2s[tid] = xb; y2s[tid] = yb;
        areas[tid] = fmaxf(xb - xa, 0.0f) * fmaxf(yb - ya, 0.0f);
    }
    __syncthreads();

    // ---- 5. suppression bit-matrix via ballot (8 waves, stride 8) ----
    {
        const float xj1a = x1s[lane], yj1a = y1s[lane];
        const float xj2a = x2s[lane], yj2a = y2s[lane], aja = areas[lane];
        const int  j2   = lane + 64;
        const bool hv2  = j2 < TOPK_PRE;
        const int  j2c  = hv2 ? j2 : 0;
        const float xj1b = x1s[j2c], yj1b = y1s[j2c];
        const float xj2b = x2s[j2c], yj2b = y2s[j2c], ajb = areas[j2c];

#pragma unroll 4
        for (int i = wid; i < TOPK_PRE; i += 8) {
            float xi1 = x1s[i], yi1 = y1s[i], xi2 = x2s[i], yi2 = y2s[i], ai = areas[i];
            bool b0 = false;
            if (lane < i) {
                float ltx = fmaxf(xi1, xj1a);
                float lty = fmaxf(yi1, yj1a);
                float rbx = fminf(xi2, xj2a);
                float rby = fminf(yi2, yj2a);
                float wx = fmaxf(rbx - ltx, 0.0f);
                float wy = fmaxf(rby - lty, 0.0f);
                float inter = wx * wy;
                float iou = inter / (((ai + aja) - inter) + 1e-7f);
                b0 = iou > IOU_THR;
            }
            u64 m0 = __ballot(b0);
            bool b1 = false;
            if (hv2 && j2 < i) {
                float ltx = fmaxf(xi1, xj1b);
                float lty = fmaxf(yi1, yj1b);
                float rbx = fminf(xi2, xj2b);
                float rby = fminf(yi2, yj2b);
                float wx = fmaxf(rbx - ltx, 0.0f);
                float wy = fmaxf(rby - lty, 0.0f);
                float inter = wx * wy;
                float iou = inter / (((ai + ajb) - inter) + 1e-7f);
                b1 = iou > IOU_THR;
            }
            u64 m1 = __ballot(b1);
            if (lane == 0) { sup0[i] = m0; sup1[i] = m1; }
        }
    }
    __syncthreads();

    // ---- 6. greedy scan with ffs-skip over alive candidates (wave 0) ----
    if (wid == 0) {
        u64 r0a = sup0[lane];
        u64 r1a = sup1[lane];
        const int  j2  = lane + 64;
        const bool hv2 = j2 < TOPK_PRE;
        u64 r0b = hv2 ? sup0[j2] : 0ull;
        u64 r1b = hv2 ? sup1[j2] : 0ull;
        bool alive_a = true;
        bool alive_b = hv2;

        // group 0: candidates 0..63 — iterate only alive ones
        {
            int i = 0;
            for (;;) {
                u64 act = __ballot(alive_a) & (~0ull << i);
                if (!act) break;
                i = __ffsll(act) - 1;
                alive_a = alive_a && !((r0a >> i) & 1ull);
                alive_b = alive_b && !((r0b >> i) & 1ull);
                if (++i >= 64) break;
            }
        }
        // group 1: candidates 64..99 (lanes 0..35 of alive_b)
        {
            int i = 0;
            for (;;) {
                u64 act = __ballot(alive_b) & (~0ull << i);
                if (!act) break;
                int m = __ffsll(act) - 1;
                if (m >= TOPK_PRE - 64) break;
                alive_a = alive_a && !((r1a >> m) & 1ull);
                alive_b = alive_b && !((r1b >> m) & 1ull);
                i = m + 1;
                if (i >= TOPK_PRE - 64) break;
            }
        }
        u64 B0 = __ballot(alive_a);
        u64 B1 = __ballot(alive_b);
        if (lane == 0) { keep0s = B0; keep1s = B1; }
    }
    __syncthreads();

    // ---- 7. write outputs: thread t takes the t-th kept row ----
    if (tid < TOPK_POST) {
        u64 K0 = keep0s, K1 = keep1s;
        int c0n = __popcll(K0);
        int idx = -1;
        if (tid < c0n) {
            u64 x = K0;
            for (int k = 0; k < tid; ++k) x &= x - 1;
            idx = __ffsll(x) - 1;
        } else {
            int t = tid - c0n;
            if (t < __popcll(K1)) {
                u64 x = K1;
                for (int k = 0; k < t; ++k) x &= x - 1;
                idx = 64 + __ffsll(x) - 1;
            }
        }
        size_t o = (size_t)row * TOPK_POST + (size_t)tid;
        float s = 0.0f, xa = 0.0f, ya = 0.0f, xb = 0.0f, yb = 0.0f;
        float lab = -1.0f, m = 0.0f;
        if (idx >= 0) {
            s = scs[idx];
            xa = x1s[idx]; ya = y1s[idx]; xb = x2s[idx]; yb = y2s[idx];
            lab = (float)labels[row];
            m = 1.0f;
        }
        out[o] = s;
        float* ob = out + 20480 + o * 4;
        ob[0] = xa; ob[1] = ya; ob[2] = xb; ob[3] = yb;
        out[102400 + o] = lab;
        out[122880 + o] = m;
    }
}

extern "C" void kernel_launch(void* const* d_in, const int* in_sizes, int n_in,
                              void* d_out, int out_size, void* d_ws, size_t ws_size,
                              hipStream_t stream) {
    const float* logits = (const float*)d_in[0];
    const float* boxes  = (const float*)d_in[1];
    const float* tsize  = (const float*)d_in[2];
    const int*   labels = (const int*)d_in[3];
    float* out = (float*)d_out;

    ovnms_kernel<<<dim3(1024), dim3(THREADS), 0, stream>>>(logits, boxes, tsize, labels, out);
}